// Round 18
// baseline (81.787 us; speedup 1.0000x reference)
//
#include <hip/hip_runtime.h>
#include <math.h>

#define NQ 12
#define DIM 4096
#define NLAYER 4
#define NT 512

typedef float v2 __attribute__((ext_vector_type(2)));
typedef float v4f __attribute__((ext_vector_type(4)));

__device__ __forceinline__ v2 sp(float a) { v2 r; r.x = a; r.y = a; return r; }
__device__ __forceinline__ v2 pkfma(v2 a, float b, v2 c) {
  return __builtin_elementwise_fma(a, sp(b), c);
}

// Compiler reorder fence; wave-private pass chain premise HW-validated R14-R17.
#define CFENCE asm volatile("" ::: "memory")

// CNOT-cascade gather map (verified R1-R17).
constexpr int sfun_c(int z) { z ^= z >> 1; z ^= z >> 2; z ^= z >> 4; z ^= z >> 8; return z & (DIM - 1); }
__device__ __forceinline__ int sfun_d(int z) { z ^= z >> 1; z ^= z >> 2; z ^= z >> 4; z ^= z >> 8; return z & (DIM - 1); }
// Swizzle v3 (HW-validated R15-R17): bit0^=z5^z6, bit1^=z4^z7, bit2^=z3^z5^z8.
constexpr int swz_c(int z) {
  const int b0 = ((z >> 5) ^ (z >> 6)) & 1;
  const int b1 = ((z >> 4) ^ (z >> 7)) & 1;
  const int b2 = ((z >> 3) ^ (z >> 5) ^ (z >> 8)) & 1;
  return z ^ b0 ^ (b1 << 1) ^ (b2 << 2);
}
__device__ __forceinline__ int swz_d(int z) {
  const int b0 = ((z >> 5) ^ (z >> 6)) & 1;
  const int b1 = ((z >> 4) ^ (z >> 7)) & 1;
  const int b2 = ((z >> 3) ^ (z >> 5) ^ (z >> 8)) & 1;
  return z ^ b0 ^ (b1 << 1) ^ (b2 << 2);
}

// Compile-time XOR byte-offset tables (swz, sfun GF(2)-linear).
// P1: j = z{9-11} ; P2: j = z{5,7,8} ; P3: j = z{0-2} (also encode) ;
// G: CNOT gather composed with P1.
struct KT { int P1[8], P2[8], P3[8], G[8]; };
constexpr KT mkKT() {
  KT k{};
  for (int j = 0; j < 8; ++j) {
    k.P1[j] = swz_c(j << 9) << 4;
    k.P2[j] = swz_c(((j & 1) << 5) | (((j >> 1) & 1) << 7) | (((j >> 2) & 1) << 8)) << 4;
    k.P3[j] = swz_c(j) << 4;
    k.G[j]  = swz_c(sfun_c(j << 9)) << 4;
  }
  return k;
}
constexpr KT KTab = mkKT();

__device__ __forceinline__ v2 block_reduce_sum2(v2 v, v2* red) {
  const int tid = threadIdx.x;
#pragma unroll
  for (int off = 32; off > 0; off >>= 1) {
    v.x += __shfl_down(v.x, off, 64);
    v.y += __shfl_down(v.y, off, 64);
  }
  if ((tid & 63) == 0) red[tid >> 6] = v;
  __syncthreads();
  if (tid == 0) {
    v2 s = sp(0.f);
#pragma unroll
    for (int i = 0; i < NT / 64; ++i) s += red[i];
    red[0] = s;
  }
  __syncthreads();
  v2 r = red[0];
  __syncthreads();
  return r;
}

// Packed complex pair update on raw b128 register quads.
__device__ __forceinline__ void apply_pair(v4f& A, v4f& B, const v4f g0, const v4f g1) {
  const v2 ar = A.lo, ai = A.hi, br = B.lo, bi = B.hi;
  const v2 nr0 = pkfma(bi, -g0.w, pkfma(br, g0.z, pkfma(ai, -g0.y, ar * sp(g0.x))));
  const v2 ni0 = pkfma(br,  g0.w, pkfma(bi, g0.z, pkfma(ar,  g0.y, ai * sp(g0.x))));
  const v2 nr1 = pkfma(bi, -g1.w, pkfma(br, g1.z, pkfma(ai, -g1.y, ar * sp(g1.x))));
  const v2 ni1 = pkfma(br,  g1.w, pkfma(bi, g1.z, pkfma(ar,  g1.y, ai * sp(g1.x))));
  A.lo = nr0; A.hi = ni0; B.lo = nr1; B.hi = ni1;
}

// 3 register gates; slot-bit i uses gate table entry Q_i (uniform -> s_load).
template <int Q0, int Q1, int Q2>
__device__ __forceinline__ void gatesR(v4f s[8], const float* __restrict__ GW) {
  constexpr int Q[3] = {Q0, Q1, Q2};
#pragma unroll
  for (int i = 0; i < 3; ++i) {
    const v4f g0 = *(const v4f*)(GW + Q[i] * 8);
    const v4f g1 = *(const v4f*)(GW + Q[i] * 8 + 4);
#pragma unroll
    for (int pe = 0; pe < 4; ++pe) {
      const int e0 = ((pe >> i) << (i + 1)) | (pe & ((1 << i) - 1));
      apply_pair(s[e0], s[e0 | (1 << i)], g0, g1);
    }
  }
}

// DPP cross-lane fetch: result = src[lane ^ mask] (VALU pipe, no LDS).
// CTRL: 0xB1 = quad_perm[1,0,3,2] (xor1), 0x4E = quad_perm[2,3,0,1] (xor2),
// 0x128 = row_ror:8 (xor8 within 16).
template <int CTRL>
__device__ __forceinline__ float dppx(float v) {
  return __builtin_bit_cast(float, __builtin_amdgcn_update_dpp(
      0, __builtin_bit_cast(int, v), CTRL, 0xF, 0xF, true));
}

// Gate on a lane-bit qubit via DPP. g = 8-float gate entry (SGPR-resident).
// role r = lane bit: new = (r?U11:U00)*self + (r?U10:U01)*partner.
template <int CTRL, int BITMASK>
__device__ __forceinline__ void dppgate(v4f s[8], const float* __restrict__ g,
                                        const int lane) {
  const bool r = (lane & BITMASK) != 0;
  const float cSx = r ? g[6] : g[0], cSy = r ? g[7] : g[1];
  const float cPx = r ? g[4] : g[2], cPy = r ? g[5] : g[3];
#pragma unroll
  for (int j = 0; j < 8; ++j) {
    const v2 re = s[j].lo, im = s[j].hi;
    v2 pre, pim;
    pre.x = dppx<CTRL>(re.x); pre.y = dppx<CTRL>(re.y);
    pim.x = dppx<CTRL>(im.x); pim.y = dppx<CTRL>(im.y);
    s[j].lo = pkfma(pim, -cPy, pkfma(pre, cPx, pkfma(im, -cSy, re * sp(cSx))));
    s[j].hi = pkfma(pre,  cPy, pkfma(pim, cPx, pkfma(re,  cSy, im * sp(cSx))));
  }
}

#define LOAD8(ADDR)                                       \
  _Pragma("unroll")                                       \
  for (int j = 0; j < 8; ++j)                             \
    s[j] = *(const v4f*)(st + ADDR[j]);
#define STORE8(ADDR)                                      \
  _Pragma("unroll")                                       \
  for (int j = 0; j < 8; ++j)                             \
    *(v4f*)(st + ADDR[j]) = s[j];

// --- prep: 48 gate matrices -> gw[48*8] in global (once per launch) ---
__global__ void prep_gates(const float* __restrict__ w, float* __restrict__ gw) {
  const int t = threadIdx.x;
  if (t < NLAYER * NQ) {
    const float* wp = w + t * 3;
    float phi = wp[0], th = wp[1], om = wp[2];
    float sn, cc, sa, ca, sb, cb;
    sincosf(0.5f * th, &sn, &cc);
    sincosf(0.5f * (phi + om), &sa, &ca);
    sincosf(0.5f * (phi - om), &sb, &cb);
    float* g = gw + t * 8;
    g[0] = ca * cc;  g[1] = -sa * cc;   // U00
    g[2] = -cb * sn; g[3] = -sb * sn;   // U01
    g[4] = cb * sn;  g[5] = -sb * sn;   // U10
    g[6] = ca * cc;  g[7] = sa * cc;    // U11
  }
}

__global__ __launch_bounds__(NT, 4) void qsim_kernel(
    const float* __restrict__ x, const float* __restrict__ gw,
    float* __restrict__ out) {
  extern __shared__ __align__(16) char smem[];
  char* st  = smem;                      // 64 KB: unit=(re0,re1,im0,im1)
  v2*   red = (v2*)(smem + DIM * 16);    // 64 B

  const int t = threadIdx.x;
  const int lane = t & 63, wave = t >> 6;
  const long r0 = 2L * blockIdx.x;

  // --- load 8 consecutive x from each of 2 rows, norms ---
  const float4* xa = (const float4*)(x + r0 * DIM) + t * 2;
  const float4* xb = (const float4*)(x + (r0 + 1) * DIM) + t * 2;
  const float4 a0 = xa[0], a1 = xa[1], b0 = xb[0], b1 = xb[1];
  const float va[8] = {a0.x, a0.y, a0.z, a0.w, a1.x, a1.y, a1.z, a1.w};
  const float vb[8] = {b0.x, b0.y, b0.z, b0.w, b1.x, b1.y, b1.z, b1.w};
  v2 ss = sp(0.f);
#pragma unroll
  for (int e = 0; e < 8; ++e) { ss.x += va[e] * va[e]; ss.y += vb[e] * vb[e]; }
  const v2 nsq = block_reduce_sum2(ss, red);
  const float n0 = sqrtf(nsq.x), n1 = sqrtf(nsq.y);
  const bool ok0 = n0 > 1e-10f, ok1 = n1 > 1e-10f;
  const float i0f = ok0 ? 1.0f / n0 : 0.f, i1f = ok1 ? 1.0f / n1 : 0.f;

  // --- pattern bases (byte offsets) ---
  // P1: z = wave | lane<<3 | j<<9                      (own: z{0-2}=wave)
  // P2: z = wave | (lane&3)<<3 | ((lane>>2)&1)<<6 | (lane>>3)<<9 | j@{5,7,8}
  // P3: z = j | lane<<3 | wave<<9                      (cross-wave; encode)
  const int baseP1 = swz_d(wave | (lane << 3)) << 4;
  const int baseP2 = swz_d(wave | ((lane & 3) << 3) | (((lane >> 2) & 1) << 6)
                           | ((lane >> 3) << 9)) << 4;
  const int baseP3 = swz_d((lane << 3) | (wave << 9)) << 4;
  const int baseG  = swz_d(sfun_d(wave | (lane << 3))) << 4;
  const int baseO  = swz_d(sfun_d(t)) << 4;
  int aP1[8], aP2[8], aP3[8], aG[8];
#pragma unroll
  for (int j = 0; j < 8; ++j) {
    aP1[j] = baseP1 ^ KTab.P1[j];
    aP2[j] = baseP2 ^ KTab.P2[j];
    aP3[j] = baseP3 ^ KTab.P3[j];
    aG[j]  = baseG ^ KTab.G[j];
  }

  // encode (P3 pattern): logical z = t*8 + e
#pragma unroll
  for (int e = 0; e < 8; ++e) {
    v4f u;
    u.x = ok0 ? va[e] * i0f : 0.015625f;
    u.y = ok1 ? vb[e] * i1f : 0.015625f;
    u.z = 0.f; u.w = 0.f;
    *(v4f*)(st + aP3[e]) = u;
  }
  __syncthreads();

  v4f s[8];
#pragma unroll
  for (int L = 0; L < NLAYER; ++L) {
    const float* GW = gw + L * (NQ * 8);

    // P1: regs z{9-11} (qubits 2,1,0) + DPP z3(q8,xor1), z4(q7,xor2), z6(q5,xor8).
    // L>=1 fuses prev layer's CNOT permutation into the read.
    if (L == 0) {
      LOAD8(aP1)
    } else {
      LOAD8(aG)
    }
    gatesR<2, 1, 0>(s, GW);
    dppgate<0xB1, 1>(s, GW + 8 * 8, lane);   // qubit 8 on z3 (lane bit 0)
    dppgate<0x4E, 2>(s, GW + 7 * 8, lane);   // qubit 7 on z4 (lane bit 1)
    dppgate<0x128, 8>(s, GW + 5 * 8, lane);  // qubit 5 on z6 (lane bit 3)
    if (L > 0) __syncthreads();  // all gather reads done before in-place writes
    STORE8(aP1)
    CFENCE;
    // P2: regs z{5,7,8} (qubits 6,4,3) — wave-private, NO barrier
    LOAD8(aP2)
    gatesR<6, 4, 3>(s, GW);
    STORE8(aP2)
    __syncthreads();             // P3 crosses waves
    // P3: regs z{0-2} (qubits 11,10,9) — thread-local in-place
    LOAD8(aP3)
    gatesR<11, 10, 9>(s, GW);
    STORE8(aP3)
    __syncthreads();             // next P1-gather / output reads everything
  }

  // --- output: final perm fused into gather; probs + renormalize, 2 rows ---
  float q0[8], q1[8];
  v2 ps = sp(0.f);
#pragma unroll
  for (int k = 0; k < 8; ++k) {
    const v4f v = *(const v4f*)(st + (baseO ^ KTab.G[k]));
    q0[k] = v.x * v.x + v.z * v.z;
    q1[k] = v.y * v.y + v.w * v.w;
    ps.x += q0[k]; ps.y += q1[k];
  }
  const v2 tot = block_reduce_sum2(ps, red);
  const bool k0 = tot.x > 1e-10f, k1 = tot.y > 1e-10f;
  const float t0 = k0 ? 1.0f / tot.x : 0.f, t1 = k1 ? 1.0f / tot.y : 0.f;
  float* o0 = out + r0 * DIM;
  float* o1 = out + (r0 + 1) * DIM;
#pragma unroll
  for (int k = 0; k < 8; ++k) {
    o0[t + k * NT] = k0 ? q0[k] * t0 : (1.0f / DIM);
    o1[t + k * NT] = k1 ? q1[k] * t1 : (1.0f / DIM);
  }
}

extern "C" void kernel_launch(void* const* d_in, const int* in_sizes, int n_in,
                              void* d_out, int out_size, void* d_ws, size_t ws_size,
                              hipStream_t stream) {
  const float* x = (const float*)d_in[0];
  const float* w = (const float*)d_in[1];
  float* out = (float*)d_out;
  float* gw = (float*)d_ws;  // 48 gates x 8 floats = 1536 B
  const int B = in_sizes[0] / DIM;
  prep_gates<<<1, 64, 0, stream>>>(w, gw);
  const size_t smem = DIM * 16 + (NT / 64) * sizeof(v2);
  qsim_kernel<<<B / 2, NT, smem, stream>>>(x, gw, out);
}